// Round 18
// baseline (107.022 us; speedup 1.0000x reference)
//
#include <hip/hip_runtime.h>
#include <hip/hip_bf16.h>
#include <cstdint>

using i32x4 = __attribute__((ext_vector_type(4))) int;

// Problem dims
#define BATCH   128
#define NPATCH  196
#define MTOT    25088   // 128*196, = 98*256 exactly
#define MT      98      // M-tiles of 256
#define DDIM    768
#define WCON    32
#define NCOLS   4096    // BATCH*WCON
#define BNC     128     // cols per block
#define NBLKG   3648    // grid: worst case itbase+BATCH = 3200+128 <= 3648

// preproc block ranges (2 rows per block for patch/concept segments)
#define PB_PAT  0
#define NPAT2   (MTOT/2)                       // 12544
#define PB_CON  (NPAT2)
#define NCON2   (NCOLS/2)                      // 2048
#define PB_IMG  (PB_CON + NCON2)
#define PB_TXT  (PB_IMG + BATCH)
#define PB_MAX  (PB_TXT + BATCH)               // 64 blocks: Maxbuf init (int4)
#define PB_CIDX (PB_MAX + 64)                  // 1 block: cidx build + ticket
#define PB_N    (PB_CIDX + 1)

// ws layout (bytes), each 256-aligned
#define PI8_OFF   0ull
#define PI8_BYTES ((size_t)MTOT*DDIM)
#define CI8_OFF   (PI8_OFF + PI8_BYTES)
#define CI8_BYTES (4096ull*DDIM)
#define SP_OFF    (CI8_OFF + CI8_BYTES)
#define SP_BYTES  ((size_t)MTOT*4)
#define SC_OFF    (SP_OFF + SP_BYTES)
#define SC_BYTES  (4096ull*4)
#define IMGN_OFF  (SC_OFF + SC_BYTES)
#define F_BYTES   (128ull*768*4)
#define TXTN_OFF  (IMGN_OFF + F_BYTES)
#define MAX_OFF   (TXTN_OFF + F_BYTES)
#define MAX_BYTES (128ull*4096*4)
#define PART_OFF  (MAX_OFF + MAX_BYTES)        // 256 floats (loss partials)
#define CIDX_OFF  (PART_OFF + 1024ull)
#define NCC_OFF   (CIDX_OFF + 4096ull*4)
#define TICK_OFF  (NCC_OFF + 64ull)
#define WS_NEED   (NCC_OFF + 256ull)

__device__ __forceinline__ void async_cp16(void* lds_p, const void* g) {
  __builtin_amdgcn_global_load_lds(
      (const __attribute__((address_space(1))) unsigned int*)g,
      (__attribute__((address_space(3))) unsigned int*)lds_p, 16, 0, 0);
}

__device__ __forceinline__ float neg_log_sigmoid(float x) {
  return (x > 0.f) ? log1pf(expf(-x)) : (log1pf(expf(x)) - x);
}

// monotone float<->int encoding for atomicMax on floats (no NaNs here)
__device__ __forceinline__ int encf(float f) {
  int i = __float_as_int(f);
  return i >= 0 ? i : (i ^ 0x7FFFFFFF);
}
__device__ __forceinline__ float decf(int e) {
  return __int_as_float(e >= 0 ? e : (e ^ 0x7FFFFFFF));
}

template<int VM>
__device__ __forceinline__ void vmwait() {
  asm volatile("s_waitcnt vmcnt(%0)" :: "n"(VM) : "memory");
}
__device__ __forceinline__ void blockbar() {
  asm volatile("" ::: "memory");
  __builtin_amdgcn_s_barrier();
  asm volatile("" ::: "memory");
}

// ---------------- unified preprocessing (norms + quant + init + cidx) -------
__global__ void preproc_kernel(const float* __restrict__ tokp, char* __restrict__ outp,
                               float* __restrict__ srowp,
                               const float* __restrict__ tokc, char* __restrict__ outc,
                               float* __restrict__ srowc,
                               const float* __restrict__ imgf, float* __restrict__ imgn,
                               const float* __restrict__ txtf, float* __restrict__ txtn,
                               const int* __restrict__ counts,
                               int* __restrict__ Maxbuf,
                               int* __restrict__ cidx, int* __restrict__ ncc,
                               int* __restrict__ tick) {
  int bid = blockIdx.x;
  int t = threadIdx.x; // 0..191

  if (bid >= PB_MAX) {
    if (bid < PB_CIDX) {
      int r = bid - PB_MAX;
      int4* dst = (int4*)(Maxbuf + (size_t)r * 8192);
      int4 pat = make_int4(0x80808080, 0x80808080, 0x80808080, 0x80808080);
      #pragma unroll
      for (int i = 0; i < 11; ++i) {
        int idx = t + i*192;
        if (idx < 2048) dst[idx] = pat;
      }
    } else {
      __shared__ int cls[128];
      __shared__ int stot;
      if (t < 128) cls[t] = counts[t];
      __syncthreads();
      if (t < 128) {
        int base = 0;
        for (int i = 0; i < t; ++i) base += cls[i];
        int cnt = cls[t];
        for (int k = 0; k < cnt; ++k) cidx[base + k] = t * 32 + k;
        if (t == 127) stot = base + cnt;
      }
      __syncthreads();
      if (t == 0) {
        int tot = stot;
        int totp = (tot + 127) & ~127;
        for (int j = tot; j < totp; ++j) cidx[j] = -1;
        ncc[0] = totp;
        tick[0] = 0;                       // reset last-block ticket each call
      }
    }
    return;
  }

  if (bid >= PB_IMG) {
    const float* in;
    float* fout;
    if (bid < PB_TXT) {
      int r = bid - PB_IMG;
      in = imgf + (size_t)r * DDIM; fout = imgn + (size_t)r * DDIM;
    } else {
      int r = bid - PB_TXT;
      in = txtf + (size_t)r * DDIM; fout = txtn + (size_t)r * DDIM;
    }
    __shared__ float sbs[3];
    float4 v = ((const float4*)in)[t];
    float ss = v.x*v.x + v.y*v.y + v.z*v.z + v.w*v.w;
    #pragma unroll
    for (int o = 32; o; o >>= 1) ss += __shfl_down(ss, o);
    if ((t & 63) == 0) sbs[t >> 6] = ss;
    __syncthreads();
    float tot = sbs[0] + sbs[1] + sbs[2];
    float scale = 1.0f / fmaxf(sqrtf(tot), 1e-12f);
    ((float4*)fout)[t] = make_float4(v.x*scale, v.y*scale, v.z*scale, v.w*scale);
    return;
  }

  // two-row quantize segments
  const float *inA, *inB;
  char *qoutA, *qoutB;
  float *srowA, *srowB;
  bool validA = true, validB = true;
  if (bid < PB_CON) {
    int r = bid * 2;
    inA = tokp + (size_t)r * DDIM;       inB = inA + DDIM;
    qoutA = outp + (size_t)r * DDIM;     qoutB = qoutA + DDIM;
    srowA = srowp + r;                   srowB = srowA + 1;
  } else {
    int r = (bid - PB_CON) * 2;
    int cnt = counts[r >> 5];
    validA = (r & 31) < cnt;
    validB = ((r & 31) + 1) < cnt;
    if (!validA && !validB) return;
    inA = tokc + (size_t)r * DDIM;       inB = inA + DDIM;
    qoutA = outc + (size_t)r * DDIM;     qoutB = qoutA + DDIM;
    srowA = srowc + r;                   srowB = srowA + 1;
  }

  __shared__ float sA[3], aA[3], sB[3], aB[3];
  float4 vA = validA ? ((const float4*)inA)[t] : make_float4(0,0,0,0);
  float4 vB = validB ? ((const float4*)inB)[t] : make_float4(0,0,0,0);
  float ssA = vA.x*vA.x + vA.y*vA.y + vA.z*vA.z + vA.w*vA.w;
  float ssB = vB.x*vB.x + vB.y*vB.y + vB.z*vB.z + vB.w*vB.w;
  float amA = fmaxf(fmaxf(fabsf(vA.x), fabsf(vA.y)), fmaxf(fabsf(vA.z), fabsf(vA.w)));
  float amB = fmaxf(fmaxf(fabsf(vB.x), fabsf(vB.y)), fmaxf(fabsf(vB.z), fabsf(vB.w)));
  #pragma unroll
  for (int o = 32; o; o >>= 1) {
    ssA += __shfl_down(ssA, o);  amA = fmaxf(amA, __shfl_down(amA, o));
    ssB += __shfl_down(ssB, o);  amB = fmaxf(amB, __shfl_down(amB, o));
  }
  if ((t & 63) == 0) {
    sA[t >> 6] = ssA; aA[t >> 6] = amA;
    sB[t >> 6] = ssB; aB[t >> 6] = amB;
  }
  __syncthreads();
  float totA = sA[0] + sA[1] + sA[2];
  float totB = sB[0] + sB[1] + sB[2];
  float amxA = fmaxf(fmaxf(aA[0], aA[1]), fmaxf(aA[2], 1e-30f));
  float amxB = fmaxf(fmaxf(aB[0], aB[1]), fmaxf(aB[2], 1e-30f));

  if (validA) {
    float qs = 127.0f / amxA;
    int qx = (int)rintf(vA.x * qs), qy = (int)rintf(vA.y * qs);
    int qz = (int)rintf(vA.z * qs), qw = (int)rintf(vA.w * qs);
    ((uint*)qoutA)[t] = (uint)(qx & 0xff) | ((uint)(qy & 0xff) << 8) |
                        ((uint)(qz & 0xff) << 16) | ((uint)(qw & 0xff) << 24);
    if (t == 0) srowA[0] = amxA / (127.0f * fmaxf(sqrtf(totA), 1e-12f));
  }
  if (validB) {
    float qs = 127.0f / amxB;
    int qx = (int)rintf(vB.x * qs), qy = (int)rintf(vB.y * qs);
    int qz = (int)rintf(vB.z * qs), qw = (int)rintf(vB.w * qs);
    ((uint*)qoutB)[t] = (uint)(qx & 0xff) | ((uint)(qy & 0xff) << 8) |
                        ((uint)(qz & 0xff) << 16) | ((uint)(qw & 0xff) << 24);
    if (t == 0) srowB[0] = amxB / (127.0f * fmaxf(sqrtf(totB), 1e-12f));
  }
}

// ---------------- GEMM body, templated on M-repeat ----------------
// MR=8: 256-row chunk (frozen R13 path). MR=4: 128-row half chunk.
template<int MR>
__device__ __forceinline__ void gemm_body(
    const char* __restrict__ Ab,          // patches + brow*DDIM
    const char* __restrict__ concepts,
    const float* __restrict__ sp,
    const float* __restrict__ sc,
    const int* __restrict__ cidx,
    int brow, int bcol, int* __restrict__ Max,
    char* lds, float* sp_lds, float* colmax, int tid) {
  constexpr int ROWS = MR * 32;          // block rows (256 or 128)
  constexpr int ACP  = ROWS / 64;        // A cps per thread per tile (4 or 2)
  constexpr int L    = ACP + 2;          // total cps per thread per tile

  const int lane = tid & 63;
  const int wid = tid >> 6;
  const int wm = wid >> 1;   // 0..1
  const int wn = wid & 1;    // 0..1

  if (tid < ROWS) sp_lds[tid] = sp[brow + tid];

  const int arow = wm*(MR*16) + (lane & 15);
  const int aslot = (lane >> 4) ^ (((lane & 15) >> 1) & 3);
  const int a_base = arow*64 + aslot*16;
  const int bcl = wn*64 + (lane & 15);
  const int b_base = 16384 + bcl*64 + aslot*16;
  const int r0 = tid >> 2;
  const int q0 = (tid & 3) ^ ((r0 >> 1) & 3);
  const int svoff = r0*DDIM + q0*16;

  const int cr0 = cidx[bcol + (tid >> 2)];
  const int cr1 = cidx[bcol + 64 + (tid >> 2)];
  const char* bp0 = concepts + (size_t)(cr0 < 0 ? 0 : cr0) * DDIM + q0*16;
  const char* bp1 = concepts + (size_t)(cr1 < 0 ? 0 : cr1) * DDIM + q0*16;

  i32x4 acc[MR][4];
  #pragma unroll
  for (int i = 0; i < MR; ++i)
    #pragma unroll
    for (int j = 0; j < 4; ++j) { i32x4 z = {0,0,0,0}; acc[i][j] = z; }

  auto stage = [&](int t, int bufi) {
    char* dst = lds + bufi * 24576;
    const int kcol = t * 64;
    #pragma unroll
    for (int k2 = 0; k2 < ACP; ++k2)
      async_cp16(dst + tid*16 + k2*4096, Ab + svoff + k2*(64*DDIM) + kcol);
    async_cp16(dst + 16384 + tid*16,        bp0 + kcol);
    async_cp16(dst + 16384 + tid*16 + 4096, bp1 + kcol);
  };

  auto compute = [&](int bufi) {
    const char* ab = lds + bufi * 24576;
    i32x4 a[MR], b[4];
    #pragma unroll
    for (int i = 0; i < MR; ++i) a[i] = *(const i32x4*)(ab + a_base + i*1024);
    #pragma unroll
    for (int j = 0; j < 4; ++j) b[j] = *(const i32x4*)(ab + b_base + j*1024);
    __builtin_amdgcn_s_setprio(1);
    #pragma unroll
    for (int i = 0; i < MR; ++i)
      #pragma unroll
      for (int j = 0; j < 4; ++j)
        acc[i][j] = __builtin_amdgcn_mfma_i32_16x16x64_i8(a[i], b[j], acc[i][j], 0, 0, 0);
    __builtin_amdgcn_s_setprio(0);
  };

#define TILE(T, VMN, DOSTAGE)                                                 \
  {                                                                           \
    if (DOSTAGE) stage((T) + 2, ((T) + 2) % 3);                               \
    vmwait<VMN>();                                                            \
    blockbar();                                                               \
    compute((T) % 3);                                                         \
    blockbar();                                                               \
  }

  stage(0, 0);
  stage(1, 1);
  TILE(0, 2*L, 1)  TILE(1, 2*L, 1)  TILE(2, 2*L, 1)  TILE(3, 2*L, 1)
  TILE(4, 2*L, 1)  TILE(5, 2*L, 1)  TILE(6, 2*L, 1)  TILE(7, 2*L, 1)
  TILE(8, 2*L, 1)  TILE(9, 2*L, 1)  TILE(10, L, 0)   TILE(11, 0, 0)
#undef TILE

  // epilogue: dequant + segmented column max (wave rows span <= 2 images)
  float cmax[4][2];
  #pragma unroll
  for (int j = 0; j < 4; ++j) { cmax[j][0] = -3e38f; cmax[j][1] = -3e38f; }
  float scv[4];
  #pragma unroll
  for (int j = 0; j < 4; ++j) {
    int oc = cidx[bcol + wn*64 + j*16 + (lane & 15)];
    scv[j] = sc[oc < 0 ? 0 : oc];
  }
  const int img0w = (brow + wm*(MR*16)) / NPATCH;
  #pragma unroll
  for (int i = 0; i < MR; ++i) {
    #pragma unroll
    for (int e = 0; e < 4; ++e) {
      int rl = wm*(MR*16) + i*16 + (lane >> 4)*4 + e;
      float spv = sp_lds[rl];
      int seg = ((brow + rl) / NPATCH) - img0w;   // 0 or 1
      #pragma unroll
      for (int j = 0; j < 4; ++j) {
        float v = (float)acc[i][j][e] * spv * scv[j];
        cmax[j][0] = (seg == 0) ? fmaxf(cmax[j][0], v) : cmax[j][0];
        cmax[j][1] = (seg == 1) ? fmaxf(cmax[j][1], v) : cmax[j][1];
      }
    }
  }
  #pragma unroll
  for (int j = 0; j < 4; ++j) {
    #pragma unroll
    for (int s = 0; s < 2; ++s) {
      float v = cmax[j][s];
      v = fmaxf(v, __shfl_xor(v, 16));
      v = fmaxf(v, __shfl_xor(v, 32));
      cmax[j][s] = v;
    }
  }
  if (lane < 16) {
    #pragma unroll
    for (int j = 0; j < 4; ++j) {
      colmax[(wm*2 + 0)*128 + wn*64 + j*16 + lane] = cmax[j][0];
      colmax[(wm*2 + 1)*128 + wn*64 + j*16 + lane] = cmax[j][1];
    }
  }
  __syncthreads();
  {
    int w = tid >> 7;          // 0..1 (wm)
    int col = tid & 127;
    int oc = cidx[bcol + col];           // original Max column; -1 = padding
    if (oc >= 0) {
      int i0 = (brow + w*(MR*16)) / NPATCH;
      int i1 = (brow + w*(MR*16) + MR*16 - 1) / NPATCH;
      atomicMax(&Max[(size_t)i0 * NCOLS + oc], encf(colmax[(w*2 + 0)*128 + col]));
      if (i1 != i0) atomicMax(&Max[(size_t)i1 * NCOLS + oc], encf(colmax[(w*2 + 1)*128 + col]));
    }
  }
}

// ---------------- RC GEMM dispatcher + IT-loss tail blocks ------------------
// Work order = blockIdx: fulls first (XCD-safe per-class contiguous-c
// swizzle), then 2*nsplit half-chunks, then 128 IT-loss blocks that execute
// in the otherwise-idle tail round, rest exit.
__global__ __launch_bounds__(256, 2)
void rc_gemm_max_kernel(const char* __restrict__ patches,
                        const char* __restrict__ concepts,
                        const float* __restrict__ sp,
                        const float* __restrict__ sc,
                        const int* __restrict__ cidx,
                        const int* __restrict__ ncc,
                        int* __restrict__ Max,
                        const float* __restrict__ imgn,
                        const float* __restrict__ txtn,
                        const float* __restrict__ lsc,
                        const float* __restrict__ lbi,
                        float* __restrict__ part) {
  __shared__ __align__(16) char lds[3 * 24576];
  __shared__ float sp_lds[256];
  __shared__ float colmax[512];   // [wm][seg][col] flattened

  const int totp = __builtin_amdgcn_readfirstlane(ncc[0]);
  const int nbn = totp >> 7;
  const int nact = MT * nbn;
  const int nfull = nact & ~511;
  const int nsplit = nact - nfull;
  const int itbase = nfull + 2*nsplit;

  const int bid0 = blockIdx.x;
  const int tid = threadIdx.x;

  if (bid0 >= itbase) {
    // ---- IT loss tail block: one image row m ----
    int m = bid0 - itbase;
    if (m >= BATCH) return;
    float* arow = (float*)lds;            // reuse GEMM LDS (3KB of 72KB)
    float* sb = arow + DDIM;
    for (int k = tid; k < DDIM; k += 256) arow[k] = imgn[(size_t)m * DDIM + k];
    __syncthreads();
    float val = 0.f;
    if (tid < 128) {
      const float4* br = (const float4*)(txtn + (size_t)tid * DDIM);
      const float4* ar = (const float4*)arow;
      float dot = 0.f;
      #pragma unroll 8
      for (int k = 0; k < DDIM/4; ++k) {
        float4 x = ar[k], y = br[k];
        dot += x.x*y.x + x.y*y.y + x.z*y.z + x.w*y.w;
      }
      float ts = expf(fminf(fmaxf(lsc[0], -10.f), 10.f));
      float logit = fminf(fmaxf(ts*dot + lbi[0], -50.f), 50.f);
      val = neg_log_sigmoid((tid == m) ? logit : -logit);
    }
    #pragma unroll
    for (int o = 32; o; o >>= 1) val += __shfl_down(val, o);
    if (tid < 128 && (tid & 63) == 0) sb[tid >> 6] = val;
    __syncthreads();
    if (tid == 0) part[m] = sb[0] + sb[1];
    return;
  }

  int c, mhalf = -1;
  if (bid0 < nfull) {
    const int cpx = nfull >> 3;                       // fulls per XCD class
    c = (bid0 & 7) * cpx + (bid0 >> 3);               // bijective, contiguous per class
  } else {
    int s = bid0 - nfull;
    c = nfull + (s >> 1);
    mhalf = s & 1;
  }
  const int mt = c / nbn;
  const int bn = c - mt * nbn;
  const int bcol = bn * BNC;

  if (mhalf < 0) {
    int brow = mt * 256;
    gemm_body<8>(patches + (size_t)brow * DDIM, concepts, sp, sc, cidx,
                 brow, bcol, Max, lds, sp_lds, colmax, tid);
  } else {
    int brow = mt * 256 + mhalf * 128;
    gemm_body<4>(patches + (size_t)brow * DDIM, concepts, sp, sc, cidx,
                 brow, bcol, Max, lds, sp_lds, colmax, tid);
  }
}

// ---------------- RC loss + last-block finalize ----------------
// 128 blocks x 128 threads. Each writes part[128+m]; the last block (ticket)
// reduces all 256 partials (fixed order -> deterministic) and writes out.
__global__ void rc_loss_kernel(const int* __restrict__ Max, const int* __restrict__ counts,
                               const float* __restrict__ sc, const float* __restrict__ bi,
                               float* __restrict__ part, int* __restrict__ tick,
                               float* __restrict__ out) {
  int m = blockIdx.x;
  int c = threadIdx.x;  // 128 threads
  float t = expf(fminf(fmaxf(sc[0], -10.f), 10.f));
  const int* row = Max + (size_t)m * NCOLS + (size_t)c * WCON;
  int cnt = counts[c];
  float s = 0.f;
  for (int w = 0; w < cnt; ++w) s += decf(row[w]);
  float S = s / (float)cnt;
  float logit = fminf(fmaxf(t*S + bi[0], -50.f), 50.f);
  float val = neg_log_sigmoid((c == m) ? logit : -logit);
  __shared__ float sb[2];
  #pragma unroll
  for (int o = 32; o; o >>= 1) val += __shfl_down(val, o);
  if ((c & 63) == 0) sb[c >> 6] = val;
  __syncthreads();
  if (c == 0) part[BATCH + m] = sb[0] + sb[1];

  // last-block finalize
  __threadfence();
  __shared__ int amlast;
  if (c == 0) amlast = (atomicAdd(tick, 1) == BATCH - 1);
  __syncthreads();
  if (!amlast) return;
  float vit = part[c];
  float vrc = part[BATCH + c];
  __shared__ float sit[2], src2[2];
  #pragma unroll
  for (int o = 32; o; o >>= 1) {
    vit += __shfl_down(vit, o);
    vrc += __shfl_down(vrc, o);
  }
  if ((c & 63) == 0) { sit[c >> 6] = vit; src2[c >> 6] = vrc; }
  __syncthreads();
  if (c == 0) {
    float it = (sit[0] + sit[1]) * (1.f / 16384.f);
    float rc = (src2[0] + src2[1]) * (1.f / 16384.f);
    out[0] = it + 0.5f * rc;
    out[1] = it;
    out[2] = rc;
  }
}

// ---------------- launch ----------------

extern "C" void kernel_launch(void* const* d_in, const int* in_sizes, int n_in,
                              void* d_out, int out_size, void* d_ws, size_t ws_size,
                              hipStream_t stream) {
  const float* image_features        = (const float*)d_in[0];
  const float* text_features         = (const float*)d_in[1];
  const float* image_token_features  = (const float*)d_in[2];
  const float* concept_text_features = (const float*)d_in[3];
  const int*   concept_counts        = (const int*)d_in[4];
  const float* logit_scale           = (const float*)d_in[5];
  const float* logit_bias            = (const float*)d_in[6];
  float* out = (float*)d_out;

  if (ws_size < WS_NEED) {
    hipMemsetAsync(d_out, 0, (size_t)out_size * sizeof(float), stream);
    return;
  }

  char* ws = (char*)d_ws;
  char*  patches_i8  = ws + PI8_OFF;
  char*  concepts_i8 = ws + CI8_OFF;
  float* sp          = (float*)(ws + SP_OFF);
  float* scq         = (float*)(ws + SC_OFF);
  float* imgn        = (float*)(ws + IMGN_OFF);
  float* txtn        = (float*)(ws + TXTN_OFF);
  int*   Maxbuf      = (int*)(ws + MAX_OFF);
  float* part        = (float*)(ws + PART_OFF);
  int*   cidx        = (int*)(ws + CIDX_OFF);
  int*   ncc         = (int*)(ws + NCC_OFF);
  int*   tick        = (int*)(ws + TICK_OFF);

  preproc_kernel<<<PB_N, 192, 0, stream>>>(
      image_token_features, patches_i8, sp,
      concept_text_features, concepts_i8, scq,
      image_features, imgn, text_features, txtn,
      concept_counts, Maxbuf, cidx, ncc, tick);

  rc_gemm_max_kernel<<<NBLKG, 256, 0, stream>>>(patches_i8, concepts_i8, sp, scq,
                                                cidx, ncc, Maxbuf,
                                                imgn, txtn, logit_scale, logit_bias, part);

  rc_loss_kernel<<<BATCH, 128, 0, stream>>>(Maxbuf, concept_counts,
                                            logit_scale, logit_bias, part, tick, out);
}

// Round 19
// 104.036 us; speedup vs baseline: 1.0287x; 1.0287x over previous
//
#include <hip/hip_runtime.h>
#include <hip/hip_bf16.h>
#include <cstdint>

using i32x4 = __attribute__((ext_vector_type(4))) int;

// Problem dims
#define BATCH   128
#define NPATCH  196
#define MTOT    25088   // 128*196, = 98*256 exactly
#define MT      98      // M-tiles of 256
#define DDIM    768
#define WCON    32
#define NCOLS   4096    // BATCH*WCON
#define BNC     128     // cols per block
#define NBLKG   3648    // grid: worst case nfull+2*nsplit <= nact+511 <= 3647

// preproc block ranges (2 rows per block for patch/concept segments)
#define PB_PAT  0
#define NPAT2   (MTOT/2)                       // 12544
#define PB_CON  (NPAT2)
#define NCON2   (NCOLS/2)                      // 2048
#define PB_IMG  (PB_CON + NCON2)
#define PB_TXT  (PB_IMG + BATCH)
#define PB_MAX  (PB_TXT + BATCH)               // 64 blocks: Maxbuf init (int4)
#define PB_CIDX (PB_MAX + 64)                  // 1 block: cidx build
#define PB_N    (PB_CIDX + 1)

// ws layout (bytes), each 256-aligned
#define PI8_OFF   0ull
#define PI8_BYTES ((size_t)MTOT*DDIM)
#define CI8_OFF   (PI8_OFF + PI8_BYTES)
#define CI8_BYTES (4096ull*DDIM)
#define SP_OFF    (CI8_OFF + CI8_BYTES)
#define SP_BYTES  ((size_t)MTOT*4)
#define SC_OFF    (SP_OFF + SP_BYTES)
#define SC_BYTES  (4096ull*4)
#define IMGN_OFF  (SC_OFF + SC_BYTES)
#define F_BYTES   (128ull*768*4)
#define TXTN_OFF  (IMGN_OFF + F_BYTES)
#define MAX_OFF   (TXTN_OFF + F_BYTES)
#define MAX_BYTES (128ull*4096*4)
#define PART_OFF  (MAX_OFF + MAX_BYTES)        // 256 floats (loss partials)
#define CIDX_OFF  (PART_OFF + 1024ull)
#define NCC_OFF   (CIDX_OFF + 4096ull*4)
#define WS_NEED   (NCC_OFF + 256ull)

__device__ __forceinline__ void async_cp16(void* lds_p, const void* g) {
  __builtin_amdgcn_global_load_lds(
      (const __attribute__((address_space(1))) unsigned int*)g,
      (__attribute__((address_space(3))) unsigned int*)lds_p, 16, 0, 0);
}

__device__ __forceinline__ float neg_log_sigmoid(float x) {
  return (x > 0.f) ? log1pf(expf(-x)) : (log1pf(expf(x)) - x);
}

// monotone float<->int encoding for atomicMax on floats (no NaNs here)
__device__ __forceinline__ int encf(float f) {
  int i = __float_as_int(f);
  return i >= 0 ? i : (i ^ 0x7FFFFFFF);
}
__device__ __forceinline__ float decf(int e) {
  return __int_as_float(e >= 0 ? e : (e ^ 0x7FFFFFFF));
}

template<int VM>
__device__ __forceinline__ void vmwait() {
  asm volatile("s_waitcnt vmcnt(%0)" :: "n"(VM) : "memory");
}
__device__ __forceinline__ void blockbar() {
  asm volatile("" ::: "memory");
  __builtin_amdgcn_s_barrier();
  asm volatile("" ::: "memory");
}

// ---------------- unified preprocessing (norms + quant + init + cidx) -------
__global__ void preproc_kernel(const float* __restrict__ tokp, char* __restrict__ outp,
                               float* __restrict__ srowp,
                               const float* __restrict__ tokc, char* __restrict__ outc,
                               float* __restrict__ srowc,
                               const float* __restrict__ imgf, float* __restrict__ imgn,
                               const float* __restrict__ txtf, float* __restrict__ txtn,
                               const int* __restrict__ counts,
                               int* __restrict__ Maxbuf,
                               int* __restrict__ cidx, int* __restrict__ ncc) {
  int bid = blockIdx.x;
  int t = threadIdx.x; // 0..191

  if (bid >= PB_MAX) {
    if (bid < PB_CIDX) {
      int r = bid - PB_MAX;
      int4* dst = (int4*)(Maxbuf + (size_t)r * 8192);
      int4 pat = make_int4(0x80808080, 0x80808080, 0x80808080, 0x80808080);
      #pragma unroll
      for (int i = 0; i < 11; ++i) {
        int idx = t + i*192;
        if (idx < 2048) dst[idx] = pat;
      }
    } else {
      __shared__ int cls[128];
      __shared__ int stot;
      if (t < 128) cls[t] = counts[t];
      __syncthreads();
      if (t < 128) {
        int base = 0;
        for (int i = 0; i < t; ++i) base += cls[i];
        int cnt = cls[t];
        for (int k = 0; k < cnt; ++k) cidx[base + k] = t * 32 + k;
        if (t == 127) stot = base + cnt;
      }
      __syncthreads();
      if (t == 0) {
        int tot = stot;
        int totp = (tot + 127) & ~127;
        for (int j = tot; j < totp; ++j) cidx[j] = -1;
        ncc[0] = totp;
      }
    }
    return;
  }

  if (bid >= PB_IMG) {
    const float* in;
    float* fout;
    if (bid < PB_TXT) {
      int r = bid - PB_IMG;
      in = imgf + (size_t)r * DDIM; fout = imgn + (size_t)r * DDIM;
    } else {
      int r = bid - PB_TXT;
      in = txtf + (size_t)r * DDIM; fout = txtn + (size_t)r * DDIM;
    }
    __shared__ float sbs[3];
    float4 v = ((const float4*)in)[t];
    float ss = v.x*v.x + v.y*v.y + v.z*v.z + v.w*v.w;
    #pragma unroll
    for (int o = 32; o; o >>= 1) ss += __shfl_down(ss, o);
    if ((t & 63) == 0) sbs[t >> 6] = ss;
    __syncthreads();
    float tot = sbs[0] + sbs[1] + sbs[2];
    float scale = 1.0f / fmaxf(sqrtf(tot), 1e-12f);
    ((float4*)fout)[t] = make_float4(v.x*scale, v.y*scale, v.z*scale, v.w*scale);
    return;
  }

  // two-row quantize segments
  const float *inA, *inB;
  char *qoutA, *qoutB;
  float *srowA, *srowB;
  bool validA = true, validB = true;
  if (bid < PB_CON) {
    int r = bid * 2;
    inA = tokp + (size_t)r * DDIM;       inB = inA + DDIM;
    qoutA = outp + (size_t)r * DDIM;     qoutB = qoutA + DDIM;
    srowA = srowp + r;                   srowB = srowA + 1;
  } else {
    int r = (bid - PB_CON) * 2;
    int cnt = counts[r >> 5];
    validA = (r & 31) < cnt;
    validB = ((r & 31) + 1) < cnt;
    if (!validA && !validB) return;
    inA = tokc + (size_t)r * DDIM;       inB = inA + DDIM;
    qoutA = outc + (size_t)r * DDIM;     qoutB = qoutA + DDIM;
    srowA = srowc + r;                   srowB = srowA + 1;
  }

  __shared__ float sA[3], aA[3], sB[3], aB[3];
  float4 vA = validA ? ((const float4*)inA)[t] : make_float4(0,0,0,0);
  float4 vB = validB ? ((const float4*)inB)[t] : make_float4(0,0,0,0);
  float ssA = vA.x*vA.x + vA.y*vA.y + vA.z*vA.z + vA.w*vA.w;
  float ssB = vB.x*vB.x + vB.y*vB.y + vB.z*vB.z + vB.w*vB.w;
  float amA = fmaxf(fmaxf(fabsf(vA.x), fabsf(vA.y)), fmaxf(fabsf(vA.z), fabsf(vA.w)));
  float amB = fmaxf(fmaxf(fabsf(vB.x), fabsf(vB.y)), fmaxf(fabsf(vB.z), fabsf(vB.w)));
  #pragma unroll
  for (int o = 32; o; o >>= 1) {
    ssA += __shfl_down(ssA, o);  amA = fmaxf(amA, __shfl_down(amA, o));
    ssB += __shfl_down(ssB, o);  amB = fmaxf(amB, __shfl_down(amB, o));
  }
  if ((t & 63) == 0) {
    sA[t >> 6] = ssA; aA[t >> 6] = amA;
    sB[t >> 6] = ssB; aB[t >> 6] = amB;
  }
  __syncthreads();
  float totA = sA[0] + sA[1] + sA[2];
  float totB = sB[0] + sB[1] + sB[2];
  float amxA = fmaxf(fmaxf(aA[0], aA[1]), fmaxf(aA[2], 1e-30f));
  float amxB = fmaxf(fmaxf(aB[0], aB[1]), fmaxf(aB[2], 1e-30f));

  if (validA) {
    float qs = 127.0f / amxA;
    int qx = (int)rintf(vA.x * qs), qy = (int)rintf(vA.y * qs);
    int qz = (int)rintf(vA.z * qs), qw = (int)rintf(vA.w * qs);
    ((uint*)qoutA)[t] = (uint)(qx & 0xff) | ((uint)(qy & 0xff) << 8) |
                        ((uint)(qz & 0xff) << 16) | ((uint)(qw & 0xff) << 24);
    if (t == 0) srowA[0] = amxA / (127.0f * fmaxf(sqrtf(totA), 1e-12f));
  }
  if (validB) {
    float qs = 127.0f / amxB;
    int qx = (int)rintf(vB.x * qs), qy = (int)rintf(vB.y * qs);
    int qz = (int)rintf(vB.z * qs), qw = (int)rintf(vB.w * qs);
    ((uint*)qoutB)[t] = (uint)(qx & 0xff) | ((uint)(qy & 0xff) << 8) |
                        ((uint)(qz & 0xff) << 16) | ((uint)(qw & 0xff) << 24);
    if (t == 0) srowB[0] = amxB / (127.0f * fmaxf(sqrtf(totB), 1e-12f));
  }
}

// ---------------- GEMM body, templated on M-repeat ----------------
// MR=8: 256-row chunk (frozen R13 path). MR=4: 128-row half chunk.
template<int MR>
__device__ __forceinline__ void gemm_body(
    const char* __restrict__ Ab,          // patches + brow*DDIM
    const char* __restrict__ concepts,
    const float* __restrict__ sp,
    const float* __restrict__ sc,
    const int* __restrict__ cidx,
    int brow, int bcol, int* __restrict__ Max,
    char* lds, float* sp_lds, float* colmax, int tid) {
  constexpr int ROWS = MR * 32;          // block rows (256 or 128)
  constexpr int ACP  = ROWS / 64;        // A cps per thread per tile (4 or 2)
  constexpr int L    = ACP + 2;          // total cps per thread per tile

  const int lane = tid & 63;
  const int wid = tid >> 6;
  const int wm = wid >> 1;   // 0..1
  const int wn = wid & 1;    // 0..1

  if (tid < ROWS) sp_lds[tid] = sp[brow + tid];

  const int arow = wm*(MR*16) + (lane & 15);
  const int aslot = (lane >> 4) ^ (((lane & 15) >> 1) & 3);
  const int a_base = arow*64 + aslot*16;
  const int bcl = wn*64 + (lane & 15);
  const int b_base = 16384 + bcl*64 + aslot*16;
  const int r0 = tid >> 2;
  const int q0 = (tid & 3) ^ ((r0 >> 1) & 3);
  const int svoff = r0*DDIM + q0*16;

  const int cr0 = cidx[bcol + (tid >> 2)];
  const int cr1 = cidx[bcol + 64 + (tid >> 2)];
  const char* bp0 = concepts + (size_t)(cr0 < 0 ? 0 : cr0) * DDIM + q0*16;
  const char* bp1 = concepts + (size_t)(cr1 < 0 ? 0 : cr1) * DDIM + q0*16;

  i32x4 acc[MR][4];
  #pragma unroll
  for (int i = 0; i < MR; ++i)
    #pragma unroll
    for (int j = 0; j < 4; ++j) { i32x4 z = {0,0,0,0}; acc[i][j] = z; }

  auto stage = [&](int t, int bufi) {
    char* dst = lds + bufi * 24576;
    const int kcol = t * 64;
    #pragma unroll
    for (int k2 = 0; k2 < ACP; ++k2)
      async_cp16(dst + tid*16 + k2*4096, Ab + svoff + k2*(64*DDIM) + kcol);
    async_cp16(dst + 16384 + tid*16,        bp0 + kcol);
    async_cp16(dst + 16384 + tid*16 + 4096, bp1 + kcol);
  };

  auto compute = [&](int bufi) {
    const char* ab = lds + bufi * 24576;
    i32x4 a[MR], b[4];
    #pragma unroll
    for (int i = 0; i < MR; ++i) a[i] = *(const i32x4*)(ab + a_base + i*1024);
    #pragma unroll
    for (int j = 0; j < 4; ++j) b[j] = *(const i32x4*)(ab + b_base + j*1024);
    __builtin_amdgcn_s_setprio(1);
    #pragma unroll
    for (int i = 0; i < MR; ++i)
      #pragma unroll
      for (int j = 0; j < 4; ++j)
        acc[i][j] = __builtin_amdgcn_mfma_i32_16x16x64_i8(a[i], b[j], acc[i][j], 0, 0, 0);
    __builtin_amdgcn_s_setprio(0);
  };

#define TILE(T, VMN, DOSTAGE)                                                 \
  {                                                                           \
    if (DOSTAGE) stage((T) + 2, ((T) + 2) % 3);                               \
    vmwait<VMN>();                                                            \
    blockbar();                                                               \
    compute((T) % 3);                                                         \
    blockbar();                                                               \
  }

  stage(0, 0);
  stage(1, 1);
  TILE(0, 2*L, 1)  TILE(1, 2*L, 1)  TILE(2, 2*L, 1)  TILE(3, 2*L, 1)
  TILE(4, 2*L, 1)  TILE(5, 2*L, 1)  TILE(6, 2*L, 1)  TILE(7, 2*L, 1)
  TILE(8, 2*L, 1)  TILE(9, 2*L, 1)  TILE(10, L, 0)   TILE(11, 0, 0)
#undef TILE

  // epilogue: dequant + segmented column max (wave rows span <= 2 images)
  float cmax[4][2];
  #pragma unroll
  for (int j = 0; j < 4; ++j) { cmax[j][0] = -3e38f; cmax[j][1] = -3e38f; }
  float scv[4];
  #pragma unroll
  for (int j = 0; j < 4; ++j) {
    int oc = cidx[bcol + wn*64 + j*16 + (lane & 15)];
    scv[j] = sc[oc < 0 ? 0 : oc];
  }
  const int img0w = (brow + wm*(MR*16)) / NPATCH;
  #pragma unroll
  for (int i = 0; i < MR; ++i) {
    #pragma unroll
    for (int e = 0; e < 4; ++e) {
      int rl = wm*(MR*16) + i*16 + (lane >> 4)*4 + e;
      float spv = sp_lds[rl];
      int seg = ((brow + rl) / NPATCH) - img0w;   // 0 or 1
      #pragma unroll
      for (int j = 0; j < 4; ++j) {
        float v = (float)acc[i][j][e] * spv * scv[j];
        cmax[j][0] = (seg == 0) ? fmaxf(cmax[j][0], v) : cmax[j][0];
        cmax[j][1] = (seg == 1) ? fmaxf(cmax[j][1], v) : cmax[j][1];
      }
    }
  }
  #pragma unroll
  for (int j = 0; j < 4; ++j) {
    #pragma unroll
    for (int s = 0; s < 2; ++s) {
      float v = cmax[j][s];
      v = fmaxf(v, __shfl_xor(v, 16));
      v = fmaxf(v, __shfl_xor(v, 32));
      cmax[j][s] = v;
    }
  }
  if (lane < 16) {
    #pragma unroll
    for (int j = 0; j < 4; ++j) {
      colmax[(wm*2 + 0)*128 + wn*64 + j*16 + lane] = cmax[j][0];
      colmax[(wm*2 + 1)*128 + wn*64 + j*16 + lane] = cmax[j][1];
    }
  }
  __syncthreads();
  {
    int w = tid >> 7;          // 0..1 (wm)
    int col = tid & 127;
    int oc = cidx[bcol + col];           // original Max column; -1 = padding
    if (oc >= 0) {
      int i0 = (brow + w*(MR*16)) / NPATCH;
      int i1 = (brow + w*(MR*16) + MR*16 - 1) / NPATCH;
      atomicMax(&Max[(size_t)i0 * NCOLS + oc], encf(colmax[(w*2 + 0)*128 + col]));
      if (i1 != i0) atomicMax(&Max[(size_t)i1 * NCOLS + oc], encf(colmax[(w*2 + 1)*128 + col]));
    }
  }
}

// ---------------- RC GEMM dispatcher (hybrid full/half, XCD-safe) -----------
// Work order = blockIdx: fulls first (bid0 < nfull, per-XCD-class contiguous-c
// swizzle; nfull is a multiple of 512 so every bid0%8 class gets nfull/8),
// then 2*nsplit half-chunks (naturally spread mod 8), rest exit.
__global__ __launch_bounds__(256, 2)
void rc_gemm_max_kernel(const char* __restrict__ patches,
                        const char* __restrict__ concepts,
                        const float* __restrict__ sp,
                        const float* __restrict__ sc,
                        const int* __restrict__ cidx,
                        const int* __restrict__ ncc,
                        int* __restrict__ Max) {
  __shared__ __align__(16) char lds[3 * 24576];
  __shared__ float sp_lds[256];
  __shared__ float colmax[512];   // [wm][seg][col] flattened

  const int totp = __builtin_amdgcn_readfirstlane(ncc[0]);
  const int nbn = totp >> 7;
  const int nact = MT * nbn;
  const int nfull = nact & ~511;
  const int nsplit = nact - nfull;

  const int bid0 = blockIdx.x;
  int c, mhalf = -1;
  if (bid0 < nfull) {
    const int cpx = nfull >> 3;                       // fulls per XCD class
    c = (bid0 & 7) * cpx + (bid0 >> 3);               // bijective, contiguous c per class
  } else if (bid0 < nfull + 2*nsplit) {
    int s = bid0 - nfull;
    c = nfull + (s >> 1);
    mhalf = s & 1;
  } else {
    return;
  }
  const int mt = c / nbn;
  const int bn = c - mt * nbn;
  const int bcol = bn * BNC;
  const int tid = threadIdx.x;

  if (mhalf < 0) {
    int brow = mt * 256;
    gemm_body<8>(patches + (size_t)brow * DDIM, concepts, sp, sc, cidx,
                 brow, bcol, Max, lds, sp_lds, colmax, tid);
  } else {
    int brow = mt * 256 + mhalf * 128;
    gemm_body<4>(patches + (size_t)brow * DDIM, concepts, sp, sc, cidx,
                 brow, bcol, Max, lds, sp_lds, colmax, tid);
  }
}

// ---------------- fused losses (per-block partials, no atomics) -------------
__global__ void loss_kernel(const float* __restrict__ imgn, const float* __restrict__ txtn,
                            const int* __restrict__ Max, const int* __restrict__ counts,
                            const float* __restrict__ sc, const float* __restrict__ bi,
                            float* __restrict__ part) {
  int bid = blockIdx.x;
  int c = threadIdx.x;  // 128 threads
  float t = expf(fminf(fmaxf(sc[0], -10.f), 10.f));
  float val;
  int m;
  if (bid < BATCH) {
    m = bid;
    __shared__ __align__(16) float arow[DDIM];
    for (int k = c; k < DDIM; k += 128) arow[k] = imgn[(size_t)m * DDIM + k];
    __syncthreads();
    const float4* br = (const float4*)(txtn + (size_t)c * DDIM);
    const float4* ar = (const float4*)arow;
    float dot = 0.f;
    #pragma unroll 8
    for (int k = 0; k < DDIM/4; ++k) {
      float4 x = ar[k], y = br[k];
      dot += x.x*y.x + x.y*y.y + x.z*y.z + x.w*y.w;
    }
    float logit = fminf(fmaxf(t*dot + bi[0], -50.f), 50.f);
    val = neg_log_sigmoid((c == m) ? logit : -logit);
  } else {
    m = bid - BATCH;
    const int* row = Max + (size_t)m * NCOLS + (size_t)c * WCON;
    int cnt = counts[c];
    float s = 0.f;
    for (int w = 0; w < cnt; ++w) s += decf(row[w]);
    float S = s / (float)cnt;
    float logit = fminf(fmaxf(t*S + bi[0], -50.f), 50.f);
    val = neg_log_sigmoid((c == m) ? logit : -logit);
  }
  __shared__ float sb[2];
  #pragma unroll
  for (int o = 32; o; o >>= 1) val += __shfl_down(val, o);
  if ((c & 63) == 0) sb[c >> 6] = val;
  __syncthreads();
  if (c == 0) part[bid] = sb[0] + sb[1];
}

__global__ void finalize_kernel(const float* __restrict__ part, float* __restrict__ out) {
  int t = threadIdx.x;   // 256 threads
  float v = part[t];
  __shared__ float sb[4];
  #pragma unroll
  for (int o = 32; o; o >>= 1) v += __shfl_down(v, o);
  if ((t & 63) == 0) sb[t >> 6] = v;
  __syncthreads();
  if (t == 0) {
    float it = (sb[0] + sb[1]) * (1.f / 16384.f);
    float rc = (sb[2] + sb[3]) * (1.f / 16384.f);
    out[0] = it + 0.5f * rc;
    out[1] = it;
    out[2] = rc;
  }
}

// ---------------- launch ----------------

extern "C" void kernel_launch(void* const* d_in, const int* in_sizes, int n_in,
                              void* d_out, int out_size, void* d_ws, size_t ws_size,
                              hipStream_t stream) {
  const float* image_features        = (const float*)d_in[0];
  const float* text_features         = (const float*)d_in[1];
  const float* image_token_features  = (const float*)d_in[2];
  const float* concept_text_features = (const float*)d_in[3];
  const int*   concept_counts        = (const int*)d_in[4];
  const float* logit_scale           = (const float*)d_in[5];
  const float* logit_bias            = (const float*)d_in[6];
  float* out = (float*)d_out;

  if (ws_size < WS_NEED) {
    hipMemsetAsync(d_out, 0, (size_t)out_size * sizeof(float), stream);
    return;
  }

  char* ws = (char*)d_ws;
  char*  patches_i8  = ws + PI8_OFF;
  char*  concepts_i8 = ws + CI8_OFF;
  float* sp          = (float*)(ws + SP_OFF);
  float* scq         = (float*)(ws + SC_OFF);
  float* imgn        = (float*)(ws + IMGN_OFF);
  float* txtn        = (float*)(ws + TXTN_OFF);
  int*   Maxbuf      = (int*)(ws + MAX_OFF);
  float* part        = (float*)(ws + PART_OFF);
  int*   cidx        = (int*)(ws + CIDX_OFF);
  int*   ncc         = (int*)(ws + NCC_OFF);

  preproc_kernel<<<PB_N, 192, 0, stream>>>(
      image_token_features, patches_i8, sp,
      concept_text_features, concepts_i8, scq,
      image_features, imgn, text_features, txtn,
      concept_counts, Maxbuf, cidx, ncc);

  rc_gemm_max_kernel<<<NBLKG, 256, 0, stream>>>(patches_i8, concepts_i8, sp, scq,
                                                cidx, ncc, Maxbuf);

  loss_kernel<<<2*BATCH, 128, 0, stream>>>(imgn, txtn, Maxbuf, concept_counts,
                                           logit_scale, logit_bias, part);
  finalize_kernel<<<1, 256, 0, stream>>>(part, out);
}